// Round 1
// baseline (774.760 us; speedup 1.0000x reference)
//
#include <hip/hip_runtime.h>
#include <cstdint>
#include <cmath>

#define TOKENS  16384
#define HIDDEN  4096
#define NEXP    256
#define TOPK    8
#define NGROUP  8
#define KDROP   4   /* n_group - topk_group */

#define BK 32
#define MT 64    /* tokens per WG */
#define NT 128   /* experts per WG */

// ---------------------------------------------------------------------------
// Kernel 1: gates = x @ W^T  (fp32 vector GEMM, LDS-tiled)
// WG = 256 threads, tile 64 tokens x 128 experts, BK = 32.
// Per-thread register tile: 4 tokens x 8 experts (2 groups of 4, stride 64).
// ---------------------------------------------------------------------------
__global__ __launch_bounds__(256, 4)
void gemm_gates(const float* __restrict__ x, const float* __restrict__ w,
                float* __restrict__ gates)
{
    __shared__ float As[BK][MT];   // 8 KB, k-major so frag reads are contiguous
    __shared__ float Bs[BK][NT];   // 16 KB

    const int tid  = threadIdx.x;
    const int wv   = tid >> 6;     // wave 0..3 -> 16-token slice
    const int lane = tid & 63;
    const int t4   = lane >> 4;    // 0..3  (token quad within wave)
    const int e16  = lane & 15;    // 0..15 (expert quad id)

    const int tokBlk = blockIdx.x >> 1;
    const int eBase  = (blockIdx.x & 1) * NT;
    const int tok0   = tokBlk * MT;

    float acc[4][8];
    #pragma unroll
    for (int i = 0; i < 4; ++i)
        #pragma unroll
        for (int j = 0; j < 8; ++j) acc[i][j] = 0.0f;

    // staging assignments
    const int at = tid >> 2;   // token 0..63 for A staging
    const int aj = tid & 3;    // float4 column 0..3 (and +4)
    const int be = tid >> 1;   // local expert 0..127 for B staging
    const int bh = tid & 1;    // k-half (16 k's each)

    const float4* xrow = (const float4*)(x + (size_t)(tok0 + at) * HIDDEN);
    const float4* wrow = (const float4*)(w + (size_t)(eBase + be) * HIDDEN);

    for (int kc = 0; kc < HIDDEN; kc += BK) {
        const int kf4 = kc >> 2;
        // global loads issued before the barrier (overlap with prior compute)
        float4 a0  = xrow[kf4 + aj];
        float4 a1  = xrow[kf4 + 4 + aj];
        float4 bv0 = wrow[kf4 + bh * 4 + 0];
        float4 bv1 = wrow[kf4 + bh * 4 + 1];
        float4 bv2 = wrow[kf4 + bh * 4 + 2];
        float4 bv3 = wrow[kf4 + bh * 4 + 3];

        __syncthreads();   // previous iteration's LDS reads complete

        As[aj * 4 + 0][at] = a0.x;
        As[aj * 4 + 1][at] = a0.y;
        As[aj * 4 + 2][at] = a0.z;
        As[aj * 4 + 3][at] = a0.w;
        As[16 + aj * 4 + 0][at] = a1.x;
        As[16 + aj * 4 + 1][at] = a1.y;
        As[16 + aj * 4 + 2][at] = a1.z;
        As[16 + aj * 4 + 3][at] = a1.w;

        const int bk0 = bh * 16;
        Bs[bk0 +  0][be] = bv0.x;  Bs[bk0 +  1][be] = bv0.y;
        Bs[bk0 +  2][be] = bv0.z;  Bs[bk0 +  3][be] = bv0.w;
        Bs[bk0 +  4][be] = bv1.x;  Bs[bk0 +  5][be] = bv1.y;
        Bs[bk0 +  6][be] = bv1.z;  Bs[bk0 +  7][be] = bv1.w;
        Bs[bk0 +  8][be] = bv2.x;  Bs[bk0 +  9][be] = bv2.y;
        Bs[bk0 + 10][be] = bv2.z;  Bs[bk0 + 11][be] = bv2.w;
        Bs[bk0 + 12][be] = bv3.x;  Bs[bk0 + 13][be] = bv3.y;
        Bs[bk0 + 14][be] = bv3.z;  Bs[bk0 + 15][be] = bv3.w;

        __syncthreads();

        #pragma unroll 8
        for (int k = 0; k < BK; ++k) {
            float4 av  = *(const float4*)&As[k][wv * 16 + t4 * 4];
            float4 b0v = *(const float4*)&Bs[k][e16 * 4];
            float4 b1v = *(const float4*)&Bs[k][64 + e16 * 4];
            float a_[4] = {av.x, av.y, av.z, av.w};
            float b_[8] = {b0v.x, b0v.y, b0v.z, b0v.w,
                           b1v.x, b1v.y, b1v.z, b1v.w};
            #pragma unroll
            for (int ti = 0; ti < 4; ++ti)
                #pragma unroll
                for (int ej = 0; ej < 8; ++ej)
                    acc[ti][ej] = fmaf(a_[ti], b_[ej], acc[ti][ej]);
        }
    }

    #pragma unroll
    for (int ti = 0; ti < 4; ++ti) {
        const int t = tok0 + wv * 16 + t4 * 4 + ti;
        float* gp = gates + (size_t)t * NEXP + eBase;
        float4 o0 = make_float4(acc[ti][0], acc[ti][1], acc[ti][2], acc[ti][3]);
        float4 o1 = make_float4(acc[ti][4], acc[ti][5], acc[ti][6], acc[ti][7]);
        *(float4*)(gp + e16 * 4)      = o0;
        *(float4*)(gp + 64 + e16 * 4) = o1;
    }
}

// ---------------------------------------------------------------------------
// Kernel 2: gating epilogue, one wave (64 lanes) per token.
// ---------------------------------------------------------------------------
__device__ __forceinline__ unsigned ordkey(float f) {
    unsigned u = __float_as_uint(f);
    return (u & 0x80000000u) ? ~u : (u | 0x80000000u);  // monotone float->uint
}

__global__ __launch_bounds__(256, 4)
void gate_epilogue(const float* __restrict__ gates,
                   const float* __restrict__ bias,
                   float* __restrict__ out)
{
    const int tid  = threadIdx.x;
    const int wv   = tid >> 6;
    const int lane = tid & 63;
    const int t    = blockIdx.x * 4 + wv;

    float4 gv = ((const float4*)(gates + (size_t)t * NEXP))[lane];
    float4 bv = ((const float4*)bias)[lane];

    float sig[4], sc[4];
    {
        float g_[4] = {gv.x, gv.y, gv.z, gv.w};
        float b_[4] = {bv.x, bv.y, bv.z, bv.w};
        #pragma unroll
        for (int i = 0; i < 4; ++i) {
            // mirror np's fp32 sigmoid: correctly-rounded exp, fp32 add/div
            float e = (float)exp(-(double)g_[i]);
            sig[i] = 1.0f / (1.0f + e);
            sc[i]  = sig[i] + b_[i];
        }
    }

    // top-2 of my 4 scores
    float m1 = fmaxf(sc[0], sc[1]);
    float m2 = fminf(sc[0], sc[1]);
    if (sc[2] > m1) { m2 = m1; m1 = sc[2]; } else m2 = fmaxf(m2, sc[2]);
    if (sc[3] > m1) { m2 = m1; m1 = sc[3]; } else m2 = fmaxf(m2, sc[3]);
    // merge across the 8 lanes of this group (group = lane>>3, 32 experts)
    #pragma unroll
    for (int off = 1; off < 8; off <<= 1) {
        float o1 = __shfl_xor(m1, off);
        float o2 = __shfl_xor(m2, off);
        float nm1 = fmaxf(m1, o1);
        float nm2 = fmaxf(fminf(m1, o1), fmaxf(m2, o2));
        m1 = nm1; m2 = nm2;
    }
    float gsum = m1 + m2;
    float gs[8];
    #pragma unroll
    for (int gi = 0; gi < 8; ++gi) gs[gi] = __shfl(gsum, gi * 8);

    // keep the KDROP smallest groups (tie -> lower index), faithful to ref
    int keepmask = 0;
    #pragma unroll
    for (int g = 0; g < 8; ++g) {
        int rank = 0;
        #pragma unroll
        for (int h = 0; h < 8; ++h)
            rank += (gs[h] < gs[g]) || (gs[h] == gs[g] && h < g);
        if (rank < KDROP) keepmask |= (1 << g);
    }
    const int kept = (keepmask >> (lane >> 3)) & 1;

    // lexicographic (value asc, index asc) keys; masked entries = +0.0
    unsigned long long key[4];
    #pragma unroll
    for (int i = 0; i < 4; ++i) {
        float sm = kept ? sc[i] : 0.0f;
        key[i] = ((unsigned long long)ordkey(sm) << 32) | (unsigned)(lane * 4 + i);
    }

    float ssum = 0.0f, myval = 0.0f;
    int myidx = 0;
    for (int r = 0; r < TOPK; ++r) {
        unsigned long long kmin = key[0];
        if (key[1] < kmin) kmin = key[1];
        if (key[2] < kmin) kmin = key[2];
        if (key[3] < kmin) kmin = key[3];
        #pragma unroll
        for (int off = 32; off >= 1; off >>= 1) {
            unsigned long long o = __shfl_xor(kmin, off);
            if (o < kmin) kmin = o;
        }
        const int id   = (int)(kmin & 0xffffffffull);
        const int src  = id >> 2;   // owning lane (uniform)
        const int slot = id & 3;    // uniform
        float vsrc = (slot == 0) ? sig[0] : (slot == 1) ? sig[1]
                   : (slot == 2) ? sig[2] : sig[3];
        float v = __shfl(vsrc, src);
        ssum += v;
        if (lane == r)   { myidx = id; myval = v; }
        if (lane == src) key[slot] = ~0ull;   // invalidate selected entry
    }

    if (lane < TOPK) {
        out[(size_t)t * TOPK + lane] = (float)myidx;                      // inds
        out[(size_t)TOKENS * TOPK + (size_t)t * TOPK + lane] =
            myval / (ssum + 1e-20f) * 2.5f;                               // sel
    }
}

// ---------------------------------------------------------------------------
extern "C" void kernel_launch(void* const* d_in, const int* in_sizes, int n_in,
                              void* d_out, int out_size, void* d_ws, size_t ws_size,
                              hipStream_t stream)
{
    const float* x    = (const float*)d_in[0];
    const float* w    = (const float*)d_in[1];
    const float* bias = (const float*)d_in[2];
    float* out   = (float*)d_out;
    float* gates = (float*)d_ws;   // 16384*256*4 = 16.8 MB scratch

    const int gemmBlocks = (TOKENS / MT) * (NEXP / NT);   // 512
    gemm_gates<<<dim3(gemmBlocks), dim3(256), 0, stream>>>(x, w, gates);
    gate_epilogue<<<dim3(TOKENS / 4), dim3(256), 0, stream>>>(gates, bias, out);
}

// Round 2
// 446.888 us; speedup vs baseline: 1.7337x; 1.7337x over previous
//
#include <hip/hip_runtime.h>
#include <hip/hip_fp16.h>
#include <cstdint>
#include <cmath>

#define TOKENS  16384
#define HIDDEN  4096
#define NEXP    256
#define TOPK    8
#define KDROP   4   /* n_group - topk_group */

typedef _Float16 f16x8  __attribute__((ext_vector_type(8)));
typedef float    f32x16 __attribute__((ext_vector_type(16)));

#define LO_SCALE 2048.0f          /* 2^11 */
#define LO_INV   (1.0f/2048.0f)

// ws layout (bytes):
//   [0, 16777216)            gates fp32 [TOKENS][NEXP]
//   [16777216, +2097152)     w_h  f16 chunk-array
//   [18874368, +2097152)     w_l  f16 chunk-array (scaled by 2^11)
#define WS_GATES_OFF 0
#define WS_WH_OFF    16777216
#define WS_WL_OFF    18874368

// ---------------------------------------------------------------------------
// Pre-kernel: split w (fp32) into f16 hi / (lo*2^11) stored in MFMA-frag
// chunk order: chunk (e,k8grp) -> cid = ((kc*2+s)*8 + e/32)*64 + hl*32 + e%32
// where kc=k/32, s=(k/16)%2, hl=(k/8)%2.  Each chunk = 8 consecutive k f16.
// ---------------------------------------------------------------------------
__global__ __launch_bounds__(256)
void wsplit(const float* __restrict__ w, _Float16* __restrict__ wh,
            _Float16* __restrict__ wl)
{
    const int idx = blockIdx.x * 256 + threadIdx.x;   // 0..131071
    const int e   = idx >> 9;                         // expert 0..255
    const int kg8 = idx & 511;                        // 8-k group
    const float4* p = (const float4*)(w + (size_t)e * HIDDEN + kg8 * 8);
    float4 f0 = p[0], f1 = p[1];
    float v[8] = {f0.x, f0.y, f0.z, f0.w, f1.x, f1.y, f1.z, f1.w};
    f16x8 hi, lo;
    #pragma unroll
    for (int i = 0; i < 8; ++i) {
        _Float16 h = (_Float16)v[i];
        hi[i] = h;
        lo[i] = (_Float16)((v[i] - (float)h) * LO_SCALE);
    }
    const int kc = kg8 >> 2, s = (kg8 >> 1) & 1, hl = kg8 & 1;
    const int cid = ((kc * 2 + s) * 8 + (e >> 5)) * 64 + hl * 32 + (e & 31);
    ((f16x8*)wh)[cid] = hi;
    ((f16x8*)wl)[cid] = lo;
}

// ---------------------------------------------------------------------------
// GEMM: gates += x @ W^T via split-f16 MFMA (3 products, 2 accumulators).
// Block: 64 tokens x 256 experts, K-split 2 (blockIdx.y). 4 waves; each wave
// has a 64x64 register tile = 2x2 MFMA tiles of 32x32.
// A (x) staged via LDS in chunk order (converted on the fly); B frags loaded
// directly from the pre-split, chunk-ordered, L2-resident w_h/w_l.
// ---------------------------------------------------------------------------
__global__ __launch_bounds__(256, 2)
void gemm_split(const float* __restrict__ x, const _Float16* __restrict__ wh,
                const _Float16* __restrict__ wl, float* __restrict__ gates)
{
    __shared__ _Float16 Ah[64 * 32];   // 4 KB, chunk-array order
    __shared__ _Float16 Al[64 * 32];   // 4 KB

    const int tid  = threadIdx.x;
    const int wv   = tid >> 6;
    const int lane = tid & 63;
    const int tok0 = blockIdx.x * 64;
    const int kcg0 = blockIdx.y * 64;   // this block's first k-chunk (of 32 k)

    // A staging: thread t loads one full chunk (8 consecutive k of one row)
    const int sm = tid >> 2;            // local token 0..63
    const int sq = tid & 3;             // which 8-k group within the 32-k chunk
    const float* xr = x + (size_t)(tok0 + sm) * HIDDEN;
    const int scid = ((sq >> 1) * 2 + (sm >> 5)) * 64 + (sq & 1) * 32 + (sm & 31);

    const f16x8* whc = (const f16x8*)wh;
    const f16x8* wlc = (const f16x8*)wl;

    f32x16 accH[2][2] = {};   // hi*hi
    f32x16 accX[2][2] = {};   // (lo*hi + hi*lo), scaled by 2^11

    for (int kc = 0; kc < 64; ++kc) {
        const int kcg = kcg0 + kc;
        // ---- global loads issued up front (hide latency over the barriers)
        const float4* ap = (const float4*)(xr + kcg * 32 + sq * 8);
        float4 f0 = ap[0];
        float4 f1 = ap[1];
        f16x8 bh[2][2], bl[2][2];   // [kstep s][n-tile c]
        #pragma unroll
        for (int s = 0; s < 2; ++s) {
            const int base = ((kcg * 2 + s) * 8 + wv * 2) * 64 + lane;
            bh[s][0] = whc[base];
            bh[s][1] = whc[base + 64];
            bl[s][0] = wlc[base];
            bl[s][1] = wlc[base + 64];
        }

        __syncthreads();   // all waves done reading previous A tile

        {   // convert + store this thread's A chunk
            float v[8] = {f0.x, f0.y, f0.z, f0.w, f1.x, f1.y, f1.z, f1.w};
            f16x8 hi, lo;
            #pragma unroll
            for (int i = 0; i < 8; ++i) {
                _Float16 h = (_Float16)v[i];
                hi[i] = h;
                lo[i] = (_Float16)((v[i] - (float)h) * LO_SCALE);
            }
            *(f16x8*)&Ah[scid * 8] = hi;
            *(f16x8*)&Al[scid * 8] = lo;
        }

        __syncthreads();   // A tile visible

        #pragma unroll
        for (int s = 0; s < 2; ++s) {
            f16x8 ah0 = *(const f16x8*)&Ah[((s * 2 + 0) * 64 + lane) * 8];
            f16x8 ah1 = *(const f16x8*)&Ah[((s * 2 + 1) * 64 + lane) * 8];
            f16x8 al0 = *(const f16x8*)&Al[((s * 2 + 0) * 64 + lane) * 8];
            f16x8 al1 = *(const f16x8*)&Al[((s * 2 + 1) * 64 + lane) * 8];

            accH[0][0] = __builtin_amdgcn_mfma_f32_32x32x16_f16(ah0, bh[s][0], accH[0][0], 0, 0, 0);
            accH[0][1] = __builtin_amdgcn_mfma_f32_32x32x16_f16(ah0, bh[s][1], accH[0][1], 0, 0, 0);
            accH[1][0] = __builtin_amdgcn_mfma_f32_32x32x16_f16(ah1, bh[s][0], accH[1][0], 0, 0, 0);
            accH[1][1] = __builtin_amdgcn_mfma_f32_32x32x16_f16(ah1, bh[s][1], accH[1][1], 0, 0, 0);
            accX[0][0] = __builtin_amdgcn_mfma_f32_32x32x16_f16(al0, bh[s][0], accX[0][0], 0, 0, 0);
            accX[0][1] = __builtin_amdgcn_mfma_f32_32x32x16_f16(al0, bh[s][1], accX[0][1], 0, 0, 0);
            accX[1][0] = __builtin_amdgcn_mfma_f32_32x32x16_f16(al1, bh[s][0], accX[1][0], 0, 0, 0);
            accX[1][1] = __builtin_amdgcn_mfma_f32_32x32x16_f16(al1, bh[s][1], accX[1][1], 0, 0, 0);
            accX[0][0] = __builtin_amdgcn_mfma_f32_32x32x16_f16(ah0, bl[s][0], accX[0][0], 0, 0, 0);
            accX[0][1] = __builtin_amdgcn_mfma_f32_32x32x16_f16(ah0, bl[s][1], accX[0][1], 0, 0, 0);
            accX[1][0] = __builtin_amdgcn_mfma_f32_32x32x16_f16(ah1, bl[s][0], accX[1][0], 0, 0, 0);
            accX[1][1] = __builtin_amdgcn_mfma_f32_32x32x16_f16(ah1, bl[s][1], accX[1][1], 0, 0, 0);
        }
    }

    // ---- epilogue: combine and atomically accumulate into gates
    const int col   = lane & 31;
    const int rbase = 4 * (lane >> 5);
    #pragma unroll
    for (int r = 0; r < 2; ++r)
        #pragma unroll
        for (int c = 0; c < 2; ++c) {
            float* gp = gates + (size_t)(tok0 + r * 32) * NEXP + wv * 64 + c * 32 + col;
            #pragma unroll
            for (int reg = 0; reg < 16; ++reg) {
                const int row = (reg & 3) + 8 * (reg >> 2) + rbase;
                atomicAdd(gp + (size_t)row * NEXP,
                          accH[r][c][reg] + accX[r][c][reg] * LO_INV);
            }
        }
}

// ---------------------------------------------------------------------------
// Gating epilogue: one wave per token. All-register top-k (no dynamic array
// indexing -> no scratch), fp32 expf.
// ---------------------------------------------------------------------------
__device__ __forceinline__ unsigned ordkey(float f) {
    unsigned u = __float_as_uint(f);
    return (u & 0x80000000u) ? ~u : (u | 0x80000000u);  // monotone float->uint
}

__global__ __launch_bounds__(256, 4)
void gate_epilogue(const float* __restrict__ gates,
                   const float* __restrict__ bias,
                   float* __restrict__ out)
{
    const int tid  = threadIdx.x;
    const int wv   = tid >> 6;
    const int lane = tid & 63;
    const int t    = blockIdx.x * 4 + wv;

    float4 gv = ((const float4*)(gates + (size_t)t * NEXP))[lane];
    float4 bv = ((const float4*)bias)[lane];

    float sig0 = 1.0f / (1.0f + expf(-gv.x));
    float sig1 = 1.0f / (1.0f + expf(-gv.y));
    float sig2 = 1.0f / (1.0f + expf(-gv.z));
    float sig3 = 1.0f / (1.0f + expf(-gv.w));
    float sc0 = sig0 + bv.x, sc1 = sig1 + bv.y;
    float sc2 = sig2 + bv.z, sc3 = sig3 + bv.w;

    // top-2 of my 4 scores
    float m1 = fmaxf(sc0, sc1);
    float m2 = fminf(sc0, sc1);
    if (sc2 > m1) { m2 = m1; m1 = sc2; } else m2 = fmaxf(m2, sc2);
    if (sc3 > m1) { m2 = m1; m1 = sc3; } else m2 = fmaxf(m2, sc3);
    // merge across the 8 lanes of this group (group = lane>>3, 32 experts)
    #pragma unroll
    for (int off = 1; off < 8; off <<= 1) {
        float o1 = __shfl_xor(m1, off);
        float o2 = __shfl_xor(m2, off);
        float nm1 = fmaxf(m1, o1);
        float nm2 = fmaxf(fminf(m1, o1), fmaxf(m2, o2));
        m1 = nm1; m2 = nm2;
    }
    float gsum = m1 + m2;
    float gs[8];
    #pragma unroll
    for (int gi = 0; gi < 8; ++gi) gs[gi] = __shfl(gsum, gi * 8);

    // keep the KDROP smallest groups (tie -> lower index), faithful to ref
    int keepmask = 0;
    #pragma unroll
    for (int g = 0; g < 8; ++g) {
        int rank = 0;
        #pragma unroll
        for (int h = 0; h < 8; ++h)
            rank += (gs[h] < gs[g]) || (gs[h] == gs[g] && h < g);
        if (rank < KDROP) keepmask |= (1 << g);
    }
    const bool kept = (keepmask >> (lane >> 3)) & 1;

    // lexicographic (value asc, index asc) keys; masked entries = +0.0
    const unsigned ib = (unsigned)(lane * 4);
    unsigned long long k0 = ((unsigned long long)ordkey(kept ? sc0 : 0.0f) << 32) | (ib + 0);
    unsigned long long k1 = ((unsigned long long)ordkey(kept ? sc1 : 0.0f) << 32) | (ib + 1);
    unsigned long long k2 = ((unsigned long long)ordkey(kept ? sc2 : 0.0f) << 32) | (ib + 2);
    unsigned long long k3 = ((unsigned long long)ordkey(kept ? sc3 : 0.0f) << 32) | (ib + 3);

    float ssum = 0.0f, myval = 0.0f;
    int myidx = 0;
    #pragma unroll
    for (int r = 0; r < TOPK; ++r) {
        unsigned long long kmin = k0 < k1 ? k0 : k1;
        if (k2 < kmin) kmin = k2;
        if (k3 < kmin) kmin = k3;
        #pragma unroll
        for (int off = 32; off >= 1; off >>= 1) {
            unsigned long long o = __shfl_xor(kmin, off);
            if (o < kmin) kmin = o;
        }
        const int id   = (int)(kmin & 0xffffffffull);
        const int src  = id >> 2;   // owning lane (wave-uniform)
        const int slot = id & 3;    // wave-uniform
        float vsrc = (slot == 0) ? sig0 : (slot == 1) ? sig1
                   : (slot == 2) ? sig2 : sig3;
        float v = __shfl(vsrc, src);
        ssum += v;
        if (lane == r) { myidx = id; myval = v; }
        const bool mine = (lane == src);
        if (mine && slot == 0) k0 = ~0ull;
        if (mine && slot == 1) k1 = ~0ull;
        if (mine && slot == 2) k2 = ~0ull;
        if (mine && slot == 3) k3 = ~0ull;
    }

    if (lane < TOPK) {
        out[(size_t)t * TOPK + lane] = (float)myidx;                      // inds
        out[(size_t)TOKENS * TOPK + (size_t)t * TOPK + lane] =
            myval / (ssum + 1e-20f) * 2.5f;                               // sel
    }
}

// ---------------------------------------------------------------------------
extern "C" void kernel_launch(void* const* d_in, const int* in_sizes, int n_in,
                              void* d_out, int out_size, void* d_ws, size_t ws_size,
                              hipStream_t stream)
{
    const float* x    = (const float*)d_in[0];
    const float* w    = (const float*)d_in[1];
    const float* bias = (const float*)d_in[2];
    float* out = (float*)d_out;

    float*     gates = (float*)((char*)d_ws + WS_GATES_OFF);
    _Float16*  wh    = (_Float16*)((char*)d_ws + WS_WH_OFF);
    _Float16*  wl    = (_Float16*)((char*)d_ws + WS_WL_OFF);

    // zero the gate accumulator (ws is re-poisoned before every launch)
    hipMemsetAsync(gates, 0, (size_t)TOKENS * NEXP * sizeof(float), stream);
    // split w into chunk-ordered f16 hi/lo
    wsplit<<<dim3(512), dim3(256), 0, stream>>>(w, wh, wl);
    // split-f16 MFMA GEMM, K-split 2, atomic accumulate
    gemm_split<<<dim3(TOKENS / 64, 2), dim3(256), 0, stream>>>(x, wh, wl, gates);
    // gating epilogue
    gate_epilogue<<<dim3(TOKENS / 4), dim3(256), 0, stream>>>(gates, bias, out);
}

// Round 3
// 431.263 us; speedup vs baseline: 1.7965x; 1.0362x over previous
//
#include <hip/hip_runtime.h>
#include <hip/hip_fp16.h>
#include <cstdint>
#include <cmath>

#define TOKENS  16384
#define HIDDEN  4096
#define NEXP    256
#define TOPK    8
#define KDROP   4   /* n_group - topk_group */

typedef _Float16 f16x8  __attribute__((ext_vector_type(8)));
typedef float    f32x16 __attribute__((ext_vector_type(16)));

#define LO_SCALE 2048.0f          /* 2^11 */
#define LO_INV   (1.0f/2048.0f)

// ws layout (bytes):
//   [0, 16777216)            gates0 fp32 [TOKENS][NEXP]   (K-half 0)
//   [16777216, +16777216)    gates1 fp32 [TOKENS][NEXP]   (K-half 1)
//   [33554432, +2097152)     w_h  f16 chunk-array
//   [35651584, +2097152)     w_l  f16 chunk-array (scaled by 2^11)
#define WS_G0_OFF 0
#define WS_G1_OFF 16777216
#define WS_WH_OFF 33554432
#define WS_WL_OFF 35651584

// ---------------------------------------------------------------------------
// Pre-kernel: split w (fp32) into f16 hi / (lo*2^11) stored in MFMA-frag
// chunk order: chunk (e,k8grp) -> cid = ((kc*2+s)*8 + e/32)*64 + hl*32 + e%32
// where kc=k/32, s=(k/16)%2, hl=(k/8)%2.  Each chunk = 8 consecutive k f16.
// ---------------------------------------------------------------------------
__global__ __launch_bounds__(256)
void wsplit(const float* __restrict__ w, _Float16* __restrict__ wh,
            _Float16* __restrict__ wl)
{
    const int idx = blockIdx.x * 256 + threadIdx.x;   // 0..131071
    const int e   = idx >> 9;                         // expert 0..255
    const int kg8 = idx & 511;                        // 8-k group
    const float4* p = (const float4*)(w + (size_t)e * HIDDEN + kg8 * 8);
    float4 f0 = p[0], f1 = p[1];
    float v[8] = {f0.x, f0.y, f0.z, f0.w, f1.x, f1.y, f1.z, f1.w};
    f16x8 hi, lo;
    #pragma unroll
    for (int i = 0; i < 8; ++i) {
        _Float16 h = (_Float16)v[i];
        hi[i] = h;
        lo[i] = (_Float16)((v[i] - (float)h) * LO_SCALE);
    }
    const int kc = kg8 >> 2, s = (kg8 >> 1) & 1, hl = kg8 & 1;
    const int cid = ((kc * 2 + s) * 8 + (e >> 5)) * 64 + hl * 32 + (e & 31);
    ((f16x8*)wh)[cid] = hi;
    ((f16x8*)wl)[cid] = lo;
}

// ---------------------------------------------------------------------------
// GEMM: gates_half = x @ W^T (one K-half per blockIdx.y) via split-f16 MFMA.
// Block: 64 tokens x 256 experts, 512 blocks total, 256 threads.
// Wave wv: experts [wv*64, wv*64+64), 2x2 MFMA tiles of 32x32.
// A double-buffered in LDS (one barrier/iter); B register-prefetched one
// iteration ahead straight from the chunk-ordered, L2-resident wh/wl.
// Plain stores into a per-K-half gates buffer (no atomics, no memset).
// ---------------------------------------------------------------------------
__global__ __launch_bounds__(256, 2)
void gemm_split(const float* __restrict__ x, const _Float16* __restrict__ wh,
                const _Float16* __restrict__ wl,
                float* __restrict__ g0, float* __restrict__ g1)
{
    __shared__ _Float16 Ah[2][64 * 32];   // 2 x 4 KB, chunk-array order
    __shared__ _Float16 Al[2][64 * 32];   // 2 x 4 KB

    const int tid  = threadIdx.x;
    const int wv   = tid >> 6;
    const int lane = tid & 63;
    const int tok0 = blockIdx.x * 64;
    const int kcg0 = blockIdx.y * 64;   // first 32-k chunk of this K-half
    float* gates_half = blockIdx.y ? g1 : g0;

    // A staging: thread t loads one 8-k chunk of one token row
    const int sm = tid >> 2;            // local token 0..63
    const int sq = tid & 3;             // 8-k group within the 32-k chunk
    const float* xr = x + (size_t)(tok0 + sm) * HIDDEN;
    const int scid = ((sq >> 1) * 2 + (sm >> 5)) * 64 + (sq & 1) * 32 + (sm & 31);

    const f16x8* whc = (const f16x8*)wh;
    const f16x8* wlc = (const f16x8*)wl;

    f32x16 accH[2][2] = {};   // hi*hi
    f32x16 accX[2][2] = {};   // (lo*hi + hi*lo), scaled by 2^11

    f16x8 bh[2][2], bl[2][2];   // current iteration's B frags [kstep s][ntile c]

    // ---- prologue: A(0) -> LDS[0], B(0) -> regs
    {
        const float4* ap = (const float4*)(xr + kcg0 * 32 + sq * 8);
        float4 f0 = ap[0];
        float4 f1 = ap[1];
        #pragma unroll
        for (int s = 0; s < 2; ++s) {
            const int base = ((kcg0 * 2 + s) * 8 + wv * 2) * 64 + lane;
            bh[s][0] = whc[base];
            bh[s][1] = whc[base + 64];
            bl[s][0] = wlc[base];
            bl[s][1] = wlc[base + 64];
        }
        float v[8] = {f0.x, f0.y, f0.z, f0.w, f1.x, f1.y, f1.z, f1.w};
        f16x8 hi, lo;
        #pragma unroll
        for (int i = 0; i < 8; ++i) {
            _Float16 h = (_Float16)v[i];
            hi[i] = h;
            lo[i] = (_Float16)((v[i] - (float)h) * LO_SCALE);
        }
        *(f16x8*)&Ah[0][scid * 8] = hi;
        *(f16x8*)&Al[0][scid * 8] = lo;
    }
    __syncthreads();

    #pragma unroll 2
    for (int kc = 0; kc < 64; ++kc) {
        const int cur  = kc & 1;
        const bool more = (kc < 63);

        // ---- prefetch next iteration (A raw + B frags) into registers
        float4 a0n, a1n;
        f16x8 bhn[2][2], bln[2][2];
        if (more) {
            const int kcg = kcg0 + kc + 1;
            const float4* ap = (const float4*)(xr + kcg * 32 + sq * 8);
            a0n = ap[0];
            a1n = ap[1];
            #pragma unroll
            for (int s = 0; s < 2; ++s) {
                const int base = ((kcg * 2 + s) * 8 + wv * 2) * 64 + lane;
                bhn[s][0] = whc[base];
                bhn[s][1] = whc[base + 64];
                bln[s][0] = wlc[base];
                bln[s][1] = wlc[base + 64];
            }
        }

        // ---- compute on LDS[cur] with current B regs (loaded last iter)
        #pragma unroll
        for (int s = 0; s < 2; ++s) {
            f16x8 ah0 = *(const f16x8*)&Ah[cur][((s * 2 + 0) * 64 + lane) * 8];
            f16x8 ah1 = *(const f16x8*)&Ah[cur][((s * 2 + 1) * 64 + lane) * 8];
            f16x8 al0 = *(const f16x8*)&Al[cur][((s * 2 + 0) * 64 + lane) * 8];
            f16x8 al1 = *(const f16x8*)&Al[cur][((s * 2 + 1) * 64 + lane) * 8];

            accH[0][0] = __builtin_amdgcn_mfma_f32_32x32x16_f16(ah0, bh[s][0], accH[0][0], 0, 0, 0);
            accH[0][1] = __builtin_amdgcn_mfma_f32_32x32x16_f16(ah0, bh[s][1], accH[0][1], 0, 0, 0);
            accH[1][0] = __builtin_amdgcn_mfma_f32_32x32x16_f16(ah1, bh[s][0], accH[1][0], 0, 0, 0);
            accH[1][1] = __builtin_amdgcn_mfma_f32_32x32x16_f16(ah1, bh[s][1], accH[1][1], 0, 0, 0);
            accX[0][0] = __builtin_amdgcn_mfma_f32_32x32x16_f16(al0, bh[s][0], accX[0][0], 0, 0, 0);
            accX[0][1] = __builtin_amdgcn_mfma_f32_32x32x16_f16(al0, bh[s][1], accX[0][1], 0, 0, 0);
            accX[1][0] = __builtin_amdgcn_mfma_f32_32x32x16_f16(al1, bh[s][0], accX[1][0], 0, 0, 0);
            accX[1][1] = __builtin_amdgcn_mfma_f32_32x32x16_f16(al1, bh[s][1], accX[1][1], 0, 0, 0);
            accX[0][0] = __builtin_amdgcn_mfma_f32_32x32x16_f16(ah0, bl[s][0], accX[0][0], 0, 0, 0);
            accX[0][1] = __builtin_amdgcn_mfma_f32_32x32x16_f16(ah0, bl[s][1], accX[0][1], 0, 0, 0);
            accX[1][0] = __builtin_amdgcn_mfma_f32_32x32x16_f16(ah1, bl[s][0], accX[1][0], 0, 0, 0);
            accX[1][1] = __builtin_amdgcn_mfma_f32_32x32x16_f16(ah1, bl[s][1], accX[1][1], 0, 0, 0);
        }

        // ---- store next A tile into the other LDS buffer; rotate B regs
        if (more) {
            float v[8] = {a0n.x, a0n.y, a0n.z, a0n.w, a1n.x, a1n.y, a1n.z, a1n.w};
            f16x8 hi, lo;
            #pragma unroll
            for (int i = 0; i < 8; ++i) {
                _Float16 h = (_Float16)v[i];
                hi[i] = h;
                lo[i] = (_Float16)((v[i] - (float)h) * LO_SCALE);
            }
            *(f16x8*)&Ah[cur ^ 1][scid * 8] = hi;
            *(f16x8*)&Al[cur ^ 1][scid * 8] = lo;
            #pragma unroll
            for (int s = 0; s < 2; ++s) {
                bh[s][0] = bhn[s][0]; bh[s][1] = bhn[s][1];
                bl[s][0] = bln[s][0]; bl[s][1] = bln[s][1];
            }
        }
        __syncthreads();
    }

    // ---- epilogue: combine hi + lo*2^-11, plain stores (no atomics)
    const int col   = lane & 31;
    const int rbase = 4 * (lane >> 5);
    #pragma unroll
    for (int r = 0; r < 2; ++r)
        #pragma unroll
        for (int c = 0; c < 2; ++c) {
            float* gp = gates_half + (size_t)(tok0 + r * 32) * NEXP + wv * 64 + c * 32 + col;
            #pragma unroll
            for (int reg = 0; reg < 16; ++reg) {
                const int row = (reg & 3) + 8 * (reg >> 2) + rbase;
                gp[(size_t)row * NEXP] = accH[r][c][reg] + accX[r][c][reg] * LO_INV;
            }
        }
}

// ---------------------------------------------------------------------------
// Gating epilogue: one wave per token; sums the two K-half gate buffers.
// All-register top-k (no dynamic array indexing -> no scratch).
// ---------------------------------------------------------------------------
__device__ __forceinline__ unsigned ordkey(float f) {
    unsigned u = __float_as_uint(f);
    return (u & 0x80000000u) ? ~u : (u | 0x80000000u);  // monotone float->uint
}

__global__ __launch_bounds__(256, 4)
void gate_epilogue(const float* __restrict__ g0,
                   const float* __restrict__ g1,
                   const float* __restrict__ bias,
                   float* __restrict__ out)
{
    const int tid  = threadIdx.x;
    const int wv   = tid >> 6;
    const int lane = tid & 63;
    const int t    = blockIdx.x * 4 + wv;

    float4 ga = ((const float4*)(g0 + (size_t)t * NEXP))[lane];
    float4 gb = ((const float4*)(g1 + (size_t)t * NEXP))[lane];
    float4 bv = ((const float4*)bias)[lane];
    float4 gv = make_float4(ga.x + gb.x, ga.y + gb.y, ga.z + gb.z, ga.w + gb.w);

    float sig0 = 1.0f / (1.0f + expf(-gv.x));
    float sig1 = 1.0f / (1.0f + expf(-gv.y));
    float sig2 = 1.0f / (1.0f + expf(-gv.z));
    float sig3 = 1.0f / (1.0f + expf(-gv.w));
    float sc0 = sig0 + bv.x, sc1 = sig1 + bv.y;
    float sc2 = sig2 + bv.z, sc3 = sig3 + bv.w;

    // top-2 of my 4 scores
    float m1 = fmaxf(sc0, sc1);
    float m2 = fminf(sc0, sc1);
    if (sc2 > m1) { m2 = m1; m1 = sc2; } else m2 = fmaxf(m2, sc2);
    if (sc3 > m1) { m2 = m1; m1 = sc3; } else m2 = fmaxf(m2, sc3);
    // merge across the 8 lanes of this group (group = lane>>3, 32 experts)
    #pragma unroll
    for (int off = 1; off < 8; off <<= 1) {
        float o1 = __shfl_xor(m1, off);
        float o2 = __shfl_xor(m2, off);
        float nm1 = fmaxf(m1, o1);
        float nm2 = fmaxf(fminf(m1, o1), fmaxf(m2, o2));
        m1 = nm1; m2 = nm2;
    }
    float gsum = m1 + m2;
    float gs[8];
    #pragma unroll
    for (int gi = 0; gi < 8; ++gi) gs[gi] = __shfl(gsum, gi * 8);

    // keep the KDROP smallest groups (tie -> lower index), faithful to ref
    int keepmask = 0;
    #pragma unroll
    for (int g = 0; g < 8; ++g) {
        int rank = 0;
        #pragma unroll
        for (int h = 0; h < 8; ++h)
            rank += (gs[h] < gs[g]) || (gs[h] == gs[g] && h < g);
        if (rank < KDROP) keepmask |= (1 << g);
    }
    const bool kept = (keepmask >> (lane >> 3)) & 1;

    // lexicographic (value asc, index asc) keys; masked entries = +0.0
    const unsigned ib = (unsigned)(lane * 4);
    unsigned long long k0 = ((unsigned long long)ordkey(kept ? sc0 : 0.0f) << 32) | (ib + 0);
    unsigned long long k1 = ((unsigned long long)ordkey(kept ? sc1 : 0.0f) << 32) | (ib + 1);
    unsigned long long k2 = ((unsigned long long)ordkey(kept ? sc2 : 0.0f) << 32) | (ib + 2);
    unsigned long long k3 = ((unsigned long long)ordkey(kept ? sc3 : 0.0f) << 32) | (ib + 3);

    float ssum = 0.0f, myval = 0.0f;
    int myidx = 0;
    #pragma unroll
    for (int r = 0; r < TOPK; ++r) {
        unsigned long long kmin = k0 < k1 ? k0 : k1;
        if (k2 < kmin) kmin = k2;
        if (k3 < kmin) kmin = k3;
        #pragma unroll
        for (int off = 32; off >= 1; off >>= 1) {
            unsigned long long o = __shfl_xor(kmin, off);
            if (o < kmin) kmin = o;
        }
        const int id   = (int)(kmin & 0xffffffffull);
        const int src  = id >> 2;   // owning lane (wave-uniform)
        const int slot = id & 3;    // wave-uniform
        float vsrc = (slot == 0) ? sig0 : (slot == 1) ? sig1
                   : (slot == 2) ? sig2 : sig3;
        float v = __shfl(vsrc, src);
        ssum += v;
        if (lane == r) { myidx = id; myval = v; }
        const bool mine = (lane == src);
        if (mine && slot == 0) k0 = ~0ull;
        if (mine && slot == 1) k1 = ~0ull;
        if (mine && slot == 2) k2 = ~0ull;
        if (mine && slot == 3) k3 = ~0ull;
    }

    if (lane < TOPK) {
        out[(size_t)t * TOPK + lane] = (float)myidx;                      // inds
        out[(size_t)TOKENS * TOPK + (size_t)t * TOPK + lane] =
            myval / (ssum + 1e-20f) * 2.5f;                               // sel
    }
}

// ---------------------------------------------------------------------------
extern "C" void kernel_launch(void* const* d_in, const int* in_sizes, int n_in,
                              void* d_out, int out_size, void* d_ws, size_t ws_size,
                              hipStream_t stream)
{
    const float* x    = (const float*)d_in[0];
    const float* w    = (const float*)d_in[1];
    const float* bias = (const float*)d_in[2];
    float* out = (float*)d_out;

    float*     g0 = (float*)((char*)d_ws + WS_G0_OFF);
    float*     g1 = (float*)((char*)d_ws + WS_G1_OFF);
    _Float16*  wh = (_Float16*)((char*)d_ws + WS_WH_OFF);
    _Float16*  wl = (_Float16*)((char*)d_ws + WS_WL_OFF);

    // split w into chunk-ordered f16 hi/lo
    wsplit<<<dim3(512), dim3(256), 0, stream>>>(w, wh, wl);
    // split-f16 MFMA GEMM, K-split 2; each half writes its own buffer
    gemm_split<<<dim3(TOKENS / 64, 2), dim3(256), 0, stream>>>(x, wh, wl, g0, g1);
    // gating epilogue sums the halves
    gate_epilogue<<<dim3(TOKENS / 4), dim3(256), 0, stream>>>(g0, g1, bias, out);
}